// Round 1
// baseline (31.567 us; speedup 1.0000x reference)
//
#include <hip/hip_runtime.h>

// ParallelLatticeModel: B=131072 rows, D=16 features, 4 lattices of 4 dims,
// E=24 ensemble columns, K=16 calibration keypoints, 16 corners per lattice.
//
// Design: one thread per row. All lookup tables (calibration keypoints,
// precomputed segment dx/slope, lattice kernels) are wave-uniform -> the
// compiler turns them into s_load (scalar pipe), and each VALU op reads at
// most one SGPR (v_fmac acc, s_k, v_w). Everything else stays in VGPRs with
// compile-time indexing only (runtime-indexed arrays would spill to scratch).

namespace {
constexpr int kB      = 131072;
constexpr int kD      = 16;
constexpr int kL1     = 4;
constexpr int kE      = 24;
constexpr int kK      = 16;
constexpr int kNV     = 16;
constexpr int kNSeg   = 15;   // K-1 segments per calibrator
constexpr int kThreads = 256;
}

// Precompute per-segment dx and slope for the piecewise-linear calibrators.
// tbl layout: [0, 240)  = dx[d][k]   (d*15+k)
//             [240,480) = slope[d][k]
__global__ void prep_tables(const float* __restrict__ cal_kp,
                            const float* __restrict__ cal_vals,
                            float* __restrict__ tbl) {
    int idx = blockIdx.x * blockDim.x + threadIdx.x;
    if (idx < kD * kNSeg) {
        int d = idx / kNSeg;
        int k = idx - d * kNSeg;
        float kp0 = cal_kp[d * kK + k];
        float kp1 = cal_kp[d * kK + k + 1];
        float v0  = cal_vals[d * kK + k];
        float v1  = cal_vals[d * kK + k + 1];
        float dx  = kp1 - kp0;
        float slope = (dx > 0.0f) ? (v1 - v0) / dx : 0.0f;
        tbl[idx]             = dx;
        tbl[kD * kNSeg + idx] = slope;
    }
}

__global__ __launch_bounds__(kThreads) void lattice_fwd(
    const float* __restrict__ x,
    const float* __restrict__ cal_kp,
    const float* __restrict__ cal_vals,
    const float* __restrict__ k1,    // [E][L1][NV]
    const float* __restrict__ k2,    // [E][1][NV]
    const float* __restrict__ tbl,   // dx[240], slope[240]
    float* __restrict__ out)         // [B][E]
{
    const int row = blockIdx.x * kThreads + threadIdx.x;

    // ---- load input row (64B, aligned) ----
    float xr[kD];
    const float4* xp = reinterpret_cast<const float4*>(x + (size_t)row * kD);
    #pragma unroll
    for (int i = 0; i < kD / 4; ++i) {
        float4 v = xp[i];
        xr[4*i+0] = v.x; xr[4*i+1] = v.y; xr[4*i+2] = v.z; xr[4*i+3] = v.w;
    }

    // ---- piecewise-linear calibration to [0,1] ----
    // interp(x) = v0 + sum_k slope_k * clamp(x - kp_k, 0, dx_k)
    float xc[kD];
    #pragma unroll
    for (int d = 0; d < kD; ++d) {
        float acc = cal_vals[d * kK];          // uniform -> SGPR
        float xv  = xr[d];
        #pragma unroll
        for (int k = 0; k < kNSeg; ++k) {
            float t = xv - cal_kp[d * kK + k];                 // v_subrev with s
            t = fminf(fmaxf(t, 0.0f), tbl[d * kNSeg + k]);     // v_med3 (1 sgpr)
            acc = fmaf(tbl[kD * kNSeg + d * kNSeg + k], t, acc); // v_fmac (1 sgpr)
        }
        xc[d] = fminf(fmaxf(acc, 0.0f), 1.0f);  // clip_inputs=True
    }

    // ---- layer-1 multilinear weights, dim 0 = MSB of corner index ----
    float w[kL1][kNV];
    #pragma unroll
    for (int l = 0; l < kL1; ++l) {
        float a = xc[4*l+0], b = xc[4*l+1], c = xc[4*l+2], dd = xc[4*l+3];
        float t2[2] = {1.0f - a, a};
        float t4[4];
        #pragma unroll
        for (int j = 0; j < 2; ++j) { t4[2*j] = t2[j]*(1.0f-b); t4[2*j+1] = t2[j]*b; }
        float t8[8];
        #pragma unroll
        for (int j = 0; j < 4; ++j) { t8[2*j] = t4[j]*(1.0f-c); t8[2*j+1] = t4[j]*c; }
        #pragma unroll
        for (int j = 0; j < 8; ++j) { w[l][2*j] = t8[j]*(1.0f-dd); w[l][2*j+1] = t8[j]*dd; }
    }

    // ---- per ensemble column: layer-1 dots + layer-2 lerp contraction ----
    float o[kE];
    #pragma unroll
    for (int e = 0; e < kE; ++e) {
        float h[kL1];
        #pragma unroll
        for (int l = 0; l < kL1; ++l) {
            const float* kk = k1 + ((e * kL1 + l) * kNV);   // uniform -> s_load x16
            float acc = 0.0f;
            #pragma unroll
            for (int c = 0; c < kNV; ++c) acc = fmaf(w[l][c], kk[c], acc);
            h[l] = fminf(fmaxf(acc, 0.0f), 1.0f);           // clip for layer 2
        }
        // layer-2: contract corners LSB-first (dim 3 is LSB)
        const float* kb = k2 + e * kNV;                      // uniform
        float h3 = h[3], g3 = 1.0f - h3;
        float v8[8];
        #pragma unroll
        for (int j = 0; j < 8; ++j) v8[j] = kb[2*j] * g3 + kb[2*j+1] * h3;
        float v4[4];
        #pragma unroll
        for (int j = 0; j < 4; ++j) v4[j] = fmaf(h[2], v8[2*j+1] - v8[2*j], v8[2*j]);
        float v2[2];
        #pragma unroll
        for (int j = 0; j < 2; ++j) v2[j] = fmaf(h[1], v4[2*j+1] - v4[2*j], v4[2*j]);
        o[e] = fmaf(h[0], v2[1] - v2[0], v2[0]);
    }

    // ---- coalesced-ish store: 6 x float4 (row*96B is 16B aligned) ----
    float4* op = reinterpret_cast<float4*>(out + (size_t)row * kE);
    #pragma unroll
    for (int i = 0; i < kE / 4; ++i) {
        float4 v;
        v.x = o[4*i+0]; v.y = o[4*i+1]; v.z = o[4*i+2]; v.w = o[4*i+3];
        op[i] = v;
    }
}

extern "C" void kernel_launch(void* const* d_in, const int* in_sizes, int n_in,
                              void* d_out, int out_size, void* d_ws, size_t ws_size,
                              hipStream_t stream) {
    const float* x        = (const float*)d_in[0];
    const float* cal_kp   = (const float*)d_in[1];
    const float* cal_vals = (const float*)d_in[2];
    const float* k1       = (const float*)d_in[3];
    const float* k2       = (const float*)d_in[4];
    float* out = (float*)d_out;
    float* tbl = (float*)d_ws;   // needs 480 floats = 1920 B

    hipLaunchKernelGGL(prep_tables, dim3(1), dim3(kThreads), 0, stream,
                       cal_kp, cal_vals, tbl);
    hipLaunchKernelGGL(lattice_fwd, dim3(kB / kThreads), dim3(kThreads), 0, stream,
                       x, cal_kp, cal_vals, k1, k2, tbl, out);
}